// Round 9
// baseline (141.360 us; speedup 1.0000x reference)
//
#include <hip/hip_runtime.h>

// YOLO v1 loss — R9: DIAGNOSTIC build (R6 streaming structure, triplicated).
// Pass 1 = phase A + phase B (real result). Pass 2 = phase A only.
// Pass 3 = phase B only. Passes 2/3 results kept alive via asm volatile;
// base pointers laundered per pass so loads cannot be CSE'd (rule #17).
// Purpose: our kernel has been below the harness fills in rocprof top-5
// since R4 — this makes it the #1 dispatch and yields real counters, plus
// the A/B duration split and warm-pass behavior discriminate between
// read-path-cap vs gather-cost vs cold-latency theories.
// Semantics identical to verified R6 (absmax 0.0).

constexpr int   NCELL_  = 8192 * 7 * 7;       // 401408
constexpr int   NF4_    = NCELL_ * 30 / 4;    // 3,010,560 float4 per tensor
constexpr int   TPB_    = 256;
constexpr int   NBLK_   = 2048;               // 8 blocks/CU
constexpr int   NTH_    = TPB_ * NBLK_;       // 524288
constexpr float CELLW_  = 1.0f / 7.0f;
constexpr float IMG_    = 448.0f;
constexpr float INV_BS_ = 1.0f / 8192.0f;

__device__ __forceinline__ float phaseA_body(
    const float* __restrict__ outp, const float* __restrict__ tgtp,
    const int* __restrict__ maskp, int gtid)
{
    float acc = 0.0f;
    const float4* o4p = reinterpret_cast<const float4*>(outp);
    const float4* t4p = reinterpret_cast<const float4*>(tgtp);

    unsigned D    = 4u * (unsigned)gtid;
    unsigned cell = D / 30u;
    int      ch   = (int)(D - cell * 30u);    // even, 0..28

    for (int i = gtid; i < NF4_; i += NTH_) {
        float4 o4 = o4p[i];
        float4 t4 = t4p[i];
        int m0 = maskp[cell];
        int m1 = maskp[(ch == 28) ? cell + 1u : cell];
        float mf0 = m0 ? 1.0f : 0.0f;
        float mf1 = m1 ? 1.0f : 0.0f;

#pragma unroll
        for (int j = 0; j < 4; ++j) {
            int   chj   = ch + j;
            bool  cross = (chj >= 30);
            int   chv   = cross ? chj - 30 : chj;
            float mf    = cross ? mf1 : mf0;
            float w = (chv >= 10) ? mf
                    : ((chv == 4) | (chv == 9)) ? 0.5f * (1.0f - mf)
                    : 0.0f;
            float ov = (j == 0) ? o4.x : (j == 1) ? o4.y : (j == 2) ? o4.z : o4.w;
            float tv = (j == 0) ? t4.x : (j == 1) ? t4.y : (j == 2) ? t4.z : t4.w;
            float d = ov - tv;
            acc += w * d * d;
        }

        cell += 69905u; ch += 2;
        if (ch >= 30) { ch -= 30; cell += 1u; }
    }
    return acc;
}

__device__ __forceinline__ float phaseB_body(
    const float* __restrict__ outp, const float* __restrict__ tgtp,
    const int* __restrict__ maskp, int gtid)
{
    if (gtid >= NCELL_) return 0.0f;
    const int c = gtid;
    const int m = maskp[c];
    if (!m) return 0.0f;

    const float2* po = reinterpret_cast<const float2*>(outp) + (size_t)c * 15;
    const float2* pt = reinterpret_cast<const float2*>(tgtp) + (size_t)c * 15;
    float2 a0 = po[0], a1 = po[1], a2 = po[2], a3 = po[3], a4 = po[4];
    float2 b0 = pt[0], b1 = pt[1], b2 = pt[2], b3 = pt[3], b4 = pt[4];
    const float o0 = a0.x, o1 = a0.y, o2 = a1.x, o3 = a1.y, o4v = a2.x;
    const float o5 = a2.y, o6 = a3.x, o7 = a3.y, o8 = a4.x, o9 = a4.y;
    const float t0 = b0.x, t1 = b0.y, t2 = b1.x, t3 = b1.y;
    const float t5 = b2.y, t6 = b3.x, t7 = b3.y, t8 = b4.x;

    const int rem = c % 49;
    const float gx = (float)(rem % 7) * CELLW_;
    const float gy = (float)(rem / 7) * CELLW_;

    const float tx = (t0 * CELLW_ + gx) * IMG_;
    const float ty = (t1 * CELLW_ + gy) * IMG_;
    const float tw = t2 * IMG_, th = t3 * IMG_;
    const float tx1 = tx - tw * 0.5f, tx2 = tx + tw * 0.5f;
    const float ty1 = ty - th * 0.5f, ty2 = ty + th * 0.5f;
    const float area_t = (tx2 - tx1) * (ty2 - ty1);

    float iou[2];
#pragma unroll
    for (int b = 0; b < 2; ++b) {
        float bx = (b == 0) ? o0 : o5;
        float by = (b == 0) ? o1 : o6;
        float bw = (b == 0) ? o2 : o7;
        float bh = (b == 0) ? o3 : o8;
        float x = (bx * CELLW_ + gx) * IMG_;
        float y = (by * CELLW_ + gy) * IMG_;
        float w = bw * IMG_, h = bh * IMG_;
        float x1 = x - w * 0.5f, x2 = x + w * 0.5f;
        float y1 = y - h * 0.5f, y2 = y + h * 0.5f;
        float iw = fmaxf(fminf(x2, tx2) - fmaxf(x1, tx1), 0.0f);
        float ih = fmaxf(fminf(y2, ty2) - fmaxf(y1, ty1), 0.0f);
        float inter = iw * ih;
        float area_o = (x2 - x1) * (y2 - y1);
        iou[b] = inter / (area_o + area_t - inter);
    }

    const int   max_id  = (iou[1] > iou[0]) ? 1 : 0;      // argmax, tie->first
    const float max_iou = fmaxf(iou[0], iou[1]);

    const float so0 = max_id ? o5 : o0;
    const float so1 = max_id ? o6 : o1;
    const float so2 = max_id ? o7 : o2;
    const float so3 = max_id ? o8 : o3;
    const float st0 = max_id ? t5 : t0;
    const float st1 = max_id ? t6 : t1;
    const float st2 = max_id ? t7 : t2;
    const float st3 = max_id ? t8 : t3;

    const float dxy0 = so0 - st0, dxy1 = so1 - st1;
    const float xy_loss = dxy0 * dxy0 + dxy1 * dxy1;

    const float dwh0 = sqrtf(so2) - sqrtf(st2);
    const float dwh1 = sqrtf(so3) - sqrtf(st3);
    const float wh_loss = dwh0 * dwh0 + dwh1 * dwh1;

    const int   id_conf = (max_iou > 0.0f) ? max_id : 0;
    const float sel_c   = id_conf ? o9 : o4v;
    const float sel_iou = (id_conf == max_id) ? max_iou : 0.0f;
    const float dcf     = sel_c - sel_iou;

    return 5.0f * (xy_loss + wh_loss) + dcf * dcf;
}

__global__ __launch_bounds__(TPB_) void yolo_partial_kernel(
    const float* __restrict__ outp, const float* __restrict__ tgtp,
    const int* __restrict__ maskp, float* __restrict__ partial)
{
    const int gtid = blockIdx.x * TPB_ + threadIdx.x;

    // ---- pass 1 (REAL): phase A + phase B, laundered base ----
    int z1 = 0; asm volatile("" : "+v"(z1));
    float acc = phaseA_body(outp + z1, tgtp + z1, maskp + z1, gtid)
              + phaseB_body(outp + z1, tgtp + z1, maskp + z1, gtid);

    // ---- pass 2 (diagnostic): phase A only ----
    int z2 = 0; asm volatile("" : "+v"(z2));
    float a2 = phaseA_body(outp + z2, tgtp + z2, maskp + z2, gtid);
    asm volatile("" :: "v"(a2));          // keep alive, contributes nothing

    // ---- pass 3 (diagnostic): phase B only ----
    int z3 = 0; asm volatile("" : "+v"(z3));
    float b3 = phaseB_body(outp + z3, tgtp + z3, maskp + z3, gtid);
    asm volatile("" :: "v"(b3));          // keep alive, contributes nothing

    // ---- reduction: wave shuffle + block partial ----
#pragma unroll
    for (int off = 32; off > 0; off >>= 1)
        acc += __shfl_down(acc, off);

    __shared__ float wsum[4];
    const int lane = threadIdx.x & 63;
    const int wid  = threadIdx.x >> 6;
    if (lane == 0) wsum[wid] = acc;
    __syncthreads();
    if (threadIdx.x == 0)
        partial[blockIdx.x] = wsum[0] + wsum[1] + wsum[2] + wsum[3];
}

__global__ __launch_bounds__(256) void yolo_reduce_kernel(
    const float* __restrict__ partial, float* __restrict__ out)
{
    float a = 0.0f;
    for (int i = threadIdx.x; i < NBLK_; i += 256)
        a += partial[i];

#pragma unroll
    for (int off = 32; off > 0; off >>= 1)
        a += __shfl_down(a, off);

    __shared__ float wsum[4];
    const int lane = threadIdx.x & 63;
    const int wid  = threadIdx.x >> 6;
    if (lane == 0) wsum[wid] = a;
    __syncthreads();
    if (threadIdx.x == 0)
        out[0] = (wsum[0] + wsum[1] + wsum[2] + wsum[3]) * INV_BS_;
}

extern "C" void kernel_launch(void* const* d_in, const int* in_sizes, int n_in,
                              void* d_out, int out_size, void* d_ws, size_t ws_size,
                              hipStream_t stream) {
    const float* outp = (const float*)d_in[0];
    const float* tgtp = (const float*)d_in[1];
    const int*   mask = (const int*)d_in[2];
    float*       res  = (float*)d_out;
    float*       part = (float*)d_ws;     // 2048 floats of scratch

    yolo_partial_kernel<<<NBLK_, TPB_, 0, stream>>>(outp, tgtp, mask, part);
    yolo_reduce_kernel<<<1, 256, 0, stream>>>(part, res);
}

// Round 10
// 116.529 us; speedup vs baseline: 1.2131x; 1.2131x over previous
//
#include <hip/hip_runtime.h>

// YOLO v1 loss, fused reduction — coalesced staging + two-stage reduce.
// (R10 = exact revert to the best verified build, R4: bench 115.1 us.)
// Shapes: output/target (8192, 7, 7, 30) f32, grid_mask_obj (8192,7,7) i32.
// Out: scalar f32 loss.
//
// Roofline evidence (R9 diagnostic, triplicated passes): demand-read rate
// 3.14 TB/s == per-direction share of the measured 6.29 TB/s copy ceiling
// (m13), with harness poison/restore writebacks (~366 MB/replay) draining
// concurrently in the write direction; warm (L3) passes run at ~12-16 TB/s
// (marginal cost of a full extra pass was ~8 us). VALUBusy 25%, occupancy
// 70%, bank conflicts 0 -> no execution-side limiter. Six structural
// variants (uncoalesced / float2+LDS / hoisted-ILP / 192t blocks / pure
// float4 stream / float4-NT) all land 35-44 us -> structure-invariant,
// memory-system-pinned.

constexpr float CELLW_  = 1.0f / 7.0f;
constexpr float IMG_    = 448.0f;
constexpr float INV_BS_ = 1.0f / 8192.0f;
constexpr int   NCELL_  = 8192 * 7 * 7;   // 401408
constexpr int   NBLK_   = NCELL_ / 256;   // 1568

__global__ __launch_bounds__(256) void yolo_partial_kernel(
    const float* __restrict__ outp, const float* __restrict__ tgtp,
    const int* __restrict__ maskp, float* __restrict__ partial)
{
    __shared__ int   lmask[256];
    __shared__ float lo[256 * 11];
    __shared__ float lt[256 * 11];

    const int tid   = threadIdx.x;
    const int cell0 = blockIdx.x * 256;   // grid exact: 401408 = 1568*256

    lmask[tid] = maskp[cell0 + tid];
    __syncthreads();                      // mask visible before the acc loop

    const float2* po = reinterpret_cast<const float2*>(outp) + (size_t)cell0 * 15;
    const float2* pt = reinterpret_cast<const float2*>(tgtp) + (size_t)cell0 * 15;

    // ---- load phase: 30 independent 8B loads, all in flight ----
    float2 vo[15], vt[15];
#pragma unroll
    for (int k = 0; k < 15; ++k) vo[k] = po[tid + 256 * k];
#pragma unroll
    for (int k = 0; k < 15; ++k) vt[k] = pt[tid + 256 * k];

    float acc = 0.0f;

    // ---- consume phase: scatter box/conf to LDS, fold cls SSE ----
    // Incremental (cell c, channel ch) for dword index d0 = 2*tid + 512*k.
    // Step 512 dwords = 17 cells + 2 channels. ch stays even -> a float2
    // never straddles a cell boundary nor the ch=9/10 regime boundary.
    int c  = (2 * tid) / 30;
    int ch = (2 * tid) - c * 30;

#pragma unroll
    for (int k = 0; k < 15; ++k) {
        float2 o2 = vo[k];
        float2 t2 = vt[k];
        if (ch < 10) {
            // box/conf channels -> LDS (stride 11, gcd(11,32)=1)
            lo[c * 11 + ch]     = o2.x;
            lo[c * 11 + ch + 1] = o2.y;
            lt[c * 11 + ch]     = t2.x;
            lt[c * 11 + ch + 1] = t2.y;
        } else {
            // cls channels: obj-masked SSE, accumulate in-register
            float dx = o2.x - t2.x;
            float dy = o2.y - t2.y;
            acc += lmask[c] ? (dx * dx + dy * dy) : 0.0f;
        }
        ch += 2; c += 17;
        if (ch >= 30) { ch -= 30; c += 1; }
    }
    __syncthreads();

    // ---- per-cell box math (thread tid owns cell cell0+tid) ----
    {
        const float* o = &lo[tid * 11];
        const float* t = &lt[tid * 11];
        const int    m = lmask[tid];

        const int rem = (cell0 + tid) % 49;  // row = rem/7 (y), col = rem%7 (x)
        const float gx = (float)(rem % 7) * CELLW_;
        const float gy = (float)(rem / 7) * CELLW_;

        // target box 0 -> pixel corners
        const float tx = (t[0] * CELLW_ + gx) * IMG_;
        const float ty = (t[1] * CELLW_ + gy) * IMG_;
        const float tw = t[2] * IMG_, th = t[3] * IMG_;
        const float tx1 = tx - tw * 0.5f, tx2 = tx + tw * 0.5f;
        const float ty1 = ty - th * 0.5f, ty2 = ty + th * 0.5f;
        const float area_t = (tx2 - tx1) * (ty2 - ty1);

        float iou[2];
#pragma unroll
        for (int b = 0; b < 2; ++b) {
            float b0 = (b == 0) ? o[0] : o[5];
            float b1 = (b == 0) ? o[1] : o[6];
            float b2 = (b == 0) ? o[2] : o[7];
            float b3 = (b == 0) ? o[3] : o[8];
            float x = (b0 * CELLW_ + gx) * IMG_;
            float y = (b1 * CELLW_ + gy) * IMG_;
            float w = b2 * IMG_, h = b3 * IMG_;
            float x1 = x - w * 0.5f, x2 = x + w * 0.5f;
            float y1 = y - h * 0.5f, y2 = y + h * 0.5f;
            float iw = fmaxf(fminf(x2, tx2) - fmaxf(x1, tx1), 0.0f);
            float ih = fmaxf(fminf(y2, ty2) - fmaxf(y1, ty1), 0.0f);
            float inter = iw * ih;
            float area_o = (x2 - x1) * (y2 - y1);
            iou[b] = inter / (area_o + area_t - inter);
        }

        const int   max_id  = (iou[1] > iou[0]) ? 1 : 0;   // argmax, tie->first
        const float max_iou = fmaxf(iou[0], iou[1]);

        // selected box (static indices via ternaries — no runtime indexing)
        const float so0 = max_id ? o[5] : o[0];
        const float so1 = max_id ? o[6] : o[1];
        const float so2 = max_id ? o[7] : o[2];
        const float so3 = max_id ? o[8] : o[3];
        const float st0 = max_id ? t[5] : t[0];
        const float st1 = max_id ? t[6] : t[1];
        const float st2 = max_id ? t[7] : t[2];
        const float st3 = max_id ? t[8] : t[3];

        const float dxy0 = so0 - st0, dxy1 = so1 - st1;
        const float xy_loss = dxy0 * dxy0 + dxy1 * dxy1;

        const float dwh0 = sqrtf(so2) - sqrtf(st2);
        const float dwh1 = sqrtf(so3) - sqrtf(st3);
        const float wh_loss = dwh0 * dwh0 + dwh1 * dwh1;

        // conf-obj term: id_conf degenerates to 0 when max_iou == 0
        const int   id_conf = (max_iou > 0.0f) ? max_id : 0;
        const float sel_c   = id_conf ? o[9] : o[4];
        const float sel_iou = (id_conf == max_id) ? max_iou : 0.0f;
        const float dcf     = sel_c - sel_iou;
        const float c_obj   = dcf * dcf;

        // noobj conf term (both boxes)
        const float dn0 = o[4] - t[4], dn1 = o[9] - t[9];
        const float c_noobj = dn0 * dn0 + dn1 * dn1;

        acc += m ? (5.0f * (xy_loss + wh_loss) + c_obj)
                 : (0.5f * c_noobj);
        // (cls term already accumulated during staging, obj-masked)
    }

    // ---- wave (64-lane) + block reduction, plain store (NO atomic) ----
#pragma unroll
    for (int off = 32; off > 0; off >>= 1)
        acc += __shfl_down(acc, off);

    __shared__ float wsum[4];
    const int lane = threadIdx.x & 63;
    const int wid  = threadIdx.x >> 6;
    if (lane == 0) wsum[wid] = acc;
    __syncthreads();
    if (threadIdx.x == 0)
        partial[blockIdx.x] = wsum[0] + wsum[1] + wsum[2] + wsum[3];
}

__global__ __launch_bounds__(256) void yolo_reduce_kernel(
    const float* __restrict__ partial, float* __restrict__ out)
{
    float a = 0.0f;
    for (int i = threadIdx.x; i < NBLK_; i += 256)
        a += partial[i];

#pragma unroll
    for (int off = 32; off > 0; off >>= 1)
        a += __shfl_down(a, off);

    __shared__ float wsum[4];
    const int lane = threadIdx.x & 63;
    const int wid  = threadIdx.x >> 6;
    if (lane == 0) wsum[wid] = a;
    __syncthreads();
    if (threadIdx.x == 0)
        out[0] = (wsum[0] + wsum[1] + wsum[2] + wsum[3]) * INV_BS_;
}

extern "C" void kernel_launch(void* const* d_in, const int* in_sizes, int n_in,
                              void* d_out, int out_size, void* d_ws, size_t ws_size,
                              hipStream_t stream) {
    const float* outp = (const float*)d_in[0];
    const float* tgtp = (const float*)d_in[1];
    const int*   mask = (const int*)d_in[2];
    float*       res  = (float*)d_out;
    float*       part = (float*)d_ws;     // 1568 floats of scratch

    const int ncell  = in_sizes[2];       // 401408
    const int blocks = ncell / 256;       // 1568 exact

    yolo_partial_kernel<<<blocks, 256, 0, stream>>>(outp, tgtp, mask, part);
    yolo_reduce_kernel<<<1, 256, 0, stream>>>(part, res);
}